// Round 8
// baseline (203.352 us; speedup 1.0000x reference)
//
#include <hip/hip_runtime.h>
#include <hip/hip_bf16.h>

// LPLayer: e = x@W^T + b; lp = relu(tanh(e@e^T)); nf = lp@e / N
// B=8, N=2048, C_IN=128, D(C_OUT)=64. All I/O fp32.
// d_out (float) = [nf (8*2048*64)] ++ [lp (8*2048*2048)]
//
// R8 = R7 with the NT-store cast fixed (ext-vector f32x4, not HIP float4).
// R7 theory: all prior rounds wrote lp as 512-B chunks at 8-KB stride
// (~1.9 TB/s effective write BW). Now: block = 32 rows x 512 cols per jtile;
// lp staged fp32 in double-buffered LDS, streamed out as 2-KB contiguous
// runs per row (NT) -> DRAM-page-friendly writes.

#define B_    8
#define N_    2048
#define D_    64
#define CIN_  128

#define BI    32            // i-rows per block
#define BJ    512           // j-cols per jtile
#define NJT   (N_ / BJ)     // 4 jtiles
#define LW    516           // sLp fp32 row stride (512 + 4: bank-conflict-free)
#define SLPB  (BI * LW)     // one sLp buffer, fp32 elems

typedef __bf16 bf16x8 __attribute__((ext_vector_type(8)));
typedef float f32x4  __attribute__((ext_vector_type(4)));
typedef float f32x16 __attribute__((ext_vector_type(16)));

union FragU { uint4 u; bf16x8 f; };

static __device__ __forceinline__ bf16x8 ld_frag(const __hip_bfloat16* p) {
    FragU fu; fu.u = *reinterpret_cast<const uint4*>(p); return fu.f;
}

static __device__ __forceinline__ void split8(const float* p, bf16x8& hi, bf16x8& lo) {
    const float4 a = *reinterpret_cast<const float4*>(p);
    const float4 b = *reinterpret_cast<const float4*>(p + 4);
    const float v[8] = {a.x, a.y, a.z, a.w, b.x, b.y, b.z, b.w};
#pragma unroll
    for (int i = 0; i < 8; i++) {
        const __bf16 h = (__bf16)v[i];
        hi[i] = h;
        lo[i] = (__bf16)(v[i] - (float)h);
    }
}

// Convert 8 consecutive fp32 (LDS) to bf16x8.
static __device__ __forceinline__ bf16x8 cvt8(const float* p) {
    const float4 a = *reinterpret_cast<const float4*>(p);
    const float4 b = *reinterpret_cast<const float4*>(p + 4);
    bf16x8 r;
    r[0] = (__bf16)a.x; r[1] = (__bf16)a.y; r[2] = (__bf16)a.z; r[3] = (__bf16)a.w;
    r[4] = (__bf16)b.x; r[5] = (__bf16)b.y; r[6] = (__bf16)b.z; r[7] = (__bf16)b.w;
    return r;
}

// ---------------------------------------------------------------------------
// Kernel 1 (unchanged): e = x @ W^T + b -> e_hi/e_lo + e_hiT ([B][64][N]).
// ---------------------------------------------------------------------------
__global__ __launch_bounds__(256) void ex_kernel(
    const float* __restrict__ x,
    const float* __restrict__ W,
    const float* __restrict__ bias,
    __hip_bfloat16* __restrict__ e_hi,
    __hip_bfloat16* __restrict__ e_lo,
    __hip_bfloat16* __restrict__ e_hiT)
{
    __shared__ __align__(16) __hip_bfloat16 sEh[64 * 72];
    __shared__ __align__(16) __hip_bfloat16 sEl[64 * 72];
    __shared__ __align__(16) __hip_bfloat16 sEt[64 * 72];   // [chan][row]

    const int tid  = threadIdx.x;
    const int w    = tid >> 6;
    const int lane = tid & 63;
    const int quad = lane >> 4;
    const int l16  = lane & 15;
    const int gr0  = blockIdx.x * 64;
    const int m0   = gr0 + w * 16;

    const float* xrow = x + (size_t)(m0 + l16) * CIN_;
    bf16x8 ah[4], al[4];
#pragma unroll
    for (int ks = 0; ks < 4; ks++)
        split8(xrow + ks * 32 + quad * 8, ah[ks], al[ks]);

    f32x4 acc[4];
#pragma unroll
    for (int nt = 0; nt < 4; nt++) acc[nt] = f32x4{0.f, 0.f, 0.f, 0.f};

#pragma unroll
    for (int ks = 0; ks < 4; ks++) {
#pragma unroll
        for (int nt = 0; nt < 4; nt++) {
            bf16x8 wh, wl;
            split8(W + (size_t)(nt * 16 + l16) * CIN_ + ks * 32 + quad * 8, wh, wl);
            acc[nt] = __builtin_amdgcn_mfma_f32_16x16x32_bf16(ah[ks], wh, acc[nt], 0, 0, 0);
            acc[nt] = __builtin_amdgcn_mfma_f32_16x16x32_bf16(ah[ks], wl, acc[nt], 0, 0, 0);
            acc[nt] = __builtin_amdgcn_mfma_f32_16x16x32_bf16(al[ks], wh, acc[nt], 0, 0, 0);
        }
    }

#pragma unroll
    for (int nt = 0; nt < 4; nt++) {
        const int chan = nt * 16 + l16;
        const float bv = bias[chan];
#pragma unroll
        for (int i = 0; i < 4; i++) {
            const int rl = w * 16 + quad * 4 + i;
            const float e = acc[nt][i] + bv;
            const __hip_bfloat16 hi = __float2bfloat16(e);
            const __hip_bfloat16 lo = __float2bfloat16(e - __bfloat162float(hi));
            sEh[rl * 72 + chan] = hi;
            sEl[rl * 72 + chan] = lo;
            sEt[chan * 72 + rl] = hi;
        }
    }
    __syncthreads();

    const int bt = gr0 >> 11, ir0 = gr0 & (N_ - 1);
#pragma unroll
    for (int p = 0; p < 2; p++) {
        const int q = tid + p * 256;
        const int r = q >> 3, c = (q & 7) * 8;
        *(uint4*)(e_hi + (size_t)(gr0 + r) * D_ + c)  = *(const uint4*)(sEh + r * 72 + c);
        *(uint4*)(e_lo + (size_t)(gr0 + r) * D_ + c)  = *(const uint4*)(sEl + r * 72 + c);
        *(uint4*)(e_hiT + ((size_t)bt * D_ + r) * N_ + ir0 + c) = *(const uint4*)(sEt + r * 72 + c);
    }
}

// ---------------------------------------------------------------------------
// Kernel 2: fused. Grid (8 b, 64 i-tiles of 32 rows) x 512 thr (8 waves).
// Per jtile (512 cols): wave w owns cols [cb=w*64, +64): 2 Gram 32x32 subtiles
// (split-MFMA), activation -> sLp[cur] fp32, same-wave PV (16x16x32), then
// barrier + linear store-phase: 32 rows x 2048-B contiguous NT runs.
// sLp double-buffered -> 1 barrier/jtile; stores drain a full jtile behind.
// ---------------------------------------------------------------------------
__global__ __launch_bounds__(512) void fused_kernel(
    const __hip_bfloat16* __restrict__ e_hi,
    const __hip_bfloat16* __restrict__ e_lo,
    const __hip_bfloat16* __restrict__ e_hiT,
    float* __restrict__ out)
{
    __shared__ __align__(16) float smem[2 * SLPB];   // 132096 B

    const int b   = blockIdx.x;              // batch; linear id%8==b -> XCD pin
    const int i0  = blockIdx.y * BI;
    const int tid = threadIdx.x;
    const int w = tid >> 6, lane = tid & 63;
    const int l32 = lane & 31, half = lane >> 5;
    const int quad = lane >> 4, l16 = lane & 15;
    const int cb = w * 64;                   // wave's col base within jtile

    // Persistent Gram A-frags (32x32x16: m=l32, k=half*8+j), K=64 -> 4 ksteps
    const __hip_bfloat16* eih = e_hi + (size_t)(b * N_ + i0 + l32) * D_;
    const __hip_bfloat16* eil = e_lo + (size_t)(b * N_ + i0 + l32) * D_;
    bf16x8 ahi[4], alo[4];
#pragma unroll
    for (int ks = 0; ks < 4; ks++) {
        ahi[ks] = ld_frag(eih + ks * 16 + half * 8);
        alo[ks] = ld_frag(eil + ks * 16 + half * 8);
    }

    f32x4 o[2][4];
#pragma unroll
    for (int mt = 0; mt < 2; mt++)
#pragma unroll
        for (int nt = 0; nt < 4; nt++) o[mt][nt] = f32x4{0.f, 0.f, 0.f, 0.f};

    float* lp_out = out + (size_t)B_ * N_ * D_;

    // Gram B row base (within batch): j0 + cb + st*32 + l32
    const __hip_bfloat16* ejh_base = e_hi + (size_t)(b * N_ + cb + l32) * D_;
    const __hip_bfloat16* ejl_base = e_lo + (size_t)(b * N_ + cb + l32) * D_;

    // prologue: prefetch Gram B-frags for jt=0 (2 subtiles x 4 ksteps)
    bf16x8 bh[2][4], bl[2][4];
#pragma unroll
    for (int st = 0; st < 2; st++)
#pragma unroll
        for (int ks = 0; ks < 4; ks++) {
            bh[st][ks] = ld_frag(ejh_base + (size_t)st * 32 * D_ + ks * 16 + half * 8);
            bl[st][ks] = ld_frag(ejl_base + (size_t)st * 32 * D_ + ks * 16 + half * 8);
        }

    int cur = 0;
    for (int jt = 0; jt < NJT; jt++) {
        const int j0 = jt * BJ;
        float* sLp = smem + cur * SLPB;

        // ---- Gram: 2 subtiles of S[32x32], split product over K=64 ----
        f32x16 s[2] = {f32x16{}, f32x16{}};
#pragma unroll
        for (int st = 0; st < 2; st++)
#pragma unroll
            for (int ks = 0; ks < 4; ks++) {
                s[st] = __builtin_amdgcn_mfma_f32_32x32x16_bf16(ahi[ks], bh[st][ks], s[st], 0, 0, 0);
                s[st] = __builtin_amdgcn_mfma_f32_32x32x16_bf16(ahi[ks], bl[st][ks], s[st], 0, 0, 0);
                s[st] = __builtin_amdgcn_mfma_f32_32x32x16_bf16(alo[ks], bh[st][ks], s[st], 0, 0, 0);
            }

        // ---- prefetch next jtile's Gram B-frags (before any store issue) ----
        const int jn = ((jt + 1) & (NJT - 1)) * BJ;
#pragma unroll
        for (int st = 0; st < 2; st++)
#pragma unroll
            for (int ks = 0; ks < 4; ks++) {
                bh[st][ks] = ld_frag(ejh_base + (size_t)(jn + st * 32) * D_ + ks * 16 + half * 8);
                bl[st][ks] = ld_frag(ejl_base + (size_t)(jn + st * 32) * D_ + ks * 16 + half * 8);
            }

        // ---- PV B-frags for THIS jtile ----
        bf16x8 bfr[2][4];
#pragma unroll
        for (int ks = 0; ks < 2; ks++)
#pragma unroll
            for (int nt = 0; nt < 4; nt++)
                bfr[ks][nt] = ld_frag(e_hiT + ((size_t)b * D_ + nt * 16 + l16) * N_
                                      + j0 + cb + ks * 32 + quad * 8);

        // ---- activation -> sLp[cur] (fp32) ----
        // 32x32 C-layout: col=l32, row=(r&3)+8*(r>>2)+4*half
#pragma unroll
        for (int st = 0; st < 2; st++)
#pragma unroll
            for (int r = 0; r < 16; r++) {
                const int rl = (r & 3) + 8 * (r >> 2) + 4 * half;
                const float tc = fmaxf(s[st][r], 0.0f);
                const float z = __builtin_amdgcn_exp2f(tc * -2.8853900817779268f);
                sLp[rl * LW + cb + st * 32 + l32] =
                    (1.0f - z) * __builtin_amdgcn_rcpf(1.0f + z);
            }

        // same-wave LDS drain (writers==readers within this wave's slice)
        __builtin_amdgcn_s_waitcnt(0xc07f);   // lgkmcnt(0)

        // ---- PV: O[32x64] += lp[32 x 64(own cols)] @ e^T, K=64 ----
#pragma unroll
        for (int ks = 0; ks < 2; ks++)
#pragma unroll
            for (int mt = 0; mt < 2; mt++) {
                const bf16x8 a = cvt8(sLp + (mt * 16 + l16) * LW + cb + ks * 32 + quad * 8);
#pragma unroll
                for (int nt = 0; nt < 4; nt++)
                    o[mt][nt] = __builtin_amdgcn_mfma_f32_16x16x32_bf16(a, bfr[ks][nt], o[mt][nt], 0, 0, 0);
            }

        // ---- all waves done writing sLp[cur] -> store-phase may read it ----
        __syncthreads();

        // ---- linear store-phase: 32 rows x 2048 B contiguous runs (NT) ----
        // thread t: row = t>>4, float4-chunk = (t&15) + p*16  (8 sweeps)
        {
            const int r = tid >> 4, c0 = (tid & 15);
            float* dst = lp_out + (size_t)(b * N_ + i0 + r) * N_ + j0;
            const float* src = sLp + r * LW;
#pragma unroll
            for (int p = 0; p < 8; p++) {
                const int c = (c0 + p * 16) * 4;
                const f32x4 vv = *(const f32x4*)(src + c);
                __builtin_nontemporal_store(vv, (f32x4*)(dst + c));
            }
        }
        cur ^= 1;   // next jtile writes the other buffer (no barrier needed:
                    // its writers conflict only with THIS buffer 2 barriers out)
    }

    // ---- epilogue: reduce 8 wave-partials, /N, store nf ----
    __syncthreads();
    float* sO = smem;   // overlay (64 KB <= 129 KB)
#pragma unroll
    for (int mt = 0; mt < 2; mt++)
#pragma unroll
        for (int nt = 0; nt < 4; nt++)
#pragma unroll
            for (int i = 0; i < 4; i++)
                sO[w * (BI * 64) + (mt * 16 + quad * 4 + i) * 64 + nt * 16 + l16] = o[mt][nt][i];
    __syncthreads();
#pragma unroll
    for (int p = 0; p < 4; p++) {
        const int q = tid + p * 512;          // 0..2047
        const int row = q >> 6, chan = q & 63;
        float v = 0.f;
#pragma unroll
        for (int hh = 0; hh < 8; hh++)
            v += sO[hh * (BI * 64) + row * 64 + chan];
        out[(size_t)(b * N_ + i0 + row) * D_ + chan] = v * (1.0f / 2048.0f);
    }
}

// ---------------------------------------------------------------------------
extern "C" void kernel_launch(void* const* d_in, const int* in_sizes, int n_in,
                              void* d_out, int out_size, void* d_ws, size_t ws_size,
                              hipStream_t stream) {
    const float* x    = (const float*)d_in[0];
    const float* W    = (const float*)d_in[1];
    const float* bias = (const float*)d_in[2];
    float* out = (float*)d_out;

    __hip_bfloat16* e_hi  = (__hip_bfloat16*)d_ws;            // [B*N][64]
    __hip_bfloat16* e_lo  = e_hi + (size_t)B_ * N_ * D_;
    __hip_bfloat16* e_hiT = e_lo + (size_t)B_ * N_ * D_;      // [B][64][N]

    ex_kernel<<<dim3(256), dim3(256), 0, stream>>>(x, W, bias, e_hi, e_lo, e_hiT);
    fused_kernel<<<dim3(8, 64), dim3(512), 0, stream>>>(e_hi, e_lo, e_hiT, out);
}